// Round 8
// baseline (135.701 us; speedup 1.0000x reference)
//
#include <hip/hip_runtime.h>

#define N_NODES 20000
#define N_EDGES 240000
#define IN_DIM  20
#define AGG_DIM 340   // 20 sender + 320 tp
#define OUT_DIM 360   // 20 mlp + 340 aggr
#define EPS_F   1e-12f
#define CAP     64    // bucket capacity per node (Binomial mean 12, max ~35)
#define WPAD    21    // LDS leading-dim pad for conflict-free W rows

// switch version, used only in the (normally never-taken) overflow path
__device__ __forceinline__ float sh_coeff(int k, float xn, float yn, float zn) {
    const float x2 = xn * xn, y2 = yn * yn, z2 = zn * zn;
    switch (k) {
        case 0:  return 0.28209479177387814f;
        case 1:  return 0.4886025119029199f * yn;
        case 2:  return 0.4886025119029199f * zn;
        case 3:  return 0.4886025119029199f * xn;
        case 4:  return 1.0925484305920792f * xn * yn;
        case 5:  return 1.0925484305920792f * yn * zn;
        case 6:  return 0.31539156525252005f * (3.0f * z2 - 1.0f);
        case 7:  return 1.0925484305920792f * xn * zn;
        case 8:  return 0.5462742152960396f * (x2 - y2);
        case 9:  return 0.5900435899266435f * yn * (3.0f * x2 - y2);
        case 10: return 2.890611442640554f  * xn * yn * zn;
        case 11: return 0.4570457994644658f * yn * (5.0f * z2 - 1.0f);
        case 12: return 0.3731763325901154f * zn * (5.0f * z2 - 3.0f);
        case 13: return 0.4570457994644658f * xn * (5.0f * z2 - 1.0f);
        case 14: return 1.445305721320277f  * zn * (x2 - y2);
        default: return 0.5900435899266435f * xn * (x2 - 3.0f * y2); // k==15
    }
}

// ------- bucket build + per-edge SH (thread per edge, fully parallel) -------
// shbuf layout: [(col*CAP + slot)][16], values ROTATED by 12 so that gather
// lane l reads element (l & 15) == sh[(l+12) & 15] directly (no bpermute).
__global__ __launch_bounds__(256) void bucket_build_sh(
    const float* __restrict__ pos,
    const int* __restrict__ ei,
    int* __restrict__ counts,      // [N_NODES]
    int* __restrict__ ovf_cnt,     // [1]
    int* __restrict__ ovf,         // [N_EDGES] (exact)
    int* __restrict__ bucket,      // [N_NODES * CAP] holds ROW
    float4* __restrict__ shbuf)    // [N_NODES * CAP * 4] (16 floats per slot)
{
    const int e = (int)(blockIdx.x * blockDim.x + threadIdx.x);
    if (e >= N_EDGES) return;
    const int row = ei[e];
    const int col = ei[N_EDGES + e];
    const int slot = atomicAdd(&counts[col], 1);
    if (slot >= CAP) { ovf[atomicAdd(ovf_cnt, 1)] = e; return; }

    const int sidx = col * CAP + slot;
    bucket[sidx] = row;

    const float rx = pos[col * 3 + 0] - pos[row * 3 + 0];
    const float ry = pos[col * 3 + 1] - pos[row * 3 + 1];
    const float rz = pos[col * 3 + 2] - pos[row * 3 + 2];
    const float rinv = rsqrtf(rx * rx + ry * ry + rz * rz + EPS_F);
    const float x = rx * rinv, y = ry * rinv, z = rz * rinv;
    const float x2 = x * x, y2 = y * y, z2 = z * z;

    const float sh0  = 0.28209479177387814f;
    const float sh1  = 0.4886025119029199f * y;
    const float sh2  = 0.4886025119029199f * z;
    const float sh3  = 0.4886025119029199f * x;
    const float sh4  = 1.0925484305920792f * x * y;
    const float sh5  = 1.0925484305920792f * y * z;
    const float sh6  = 0.31539156525252005f * (3.0f * z2 - 1.0f);
    const float sh7  = 1.0925484305920792f * x * z;
    const float sh8  = 0.5462742152960396f * (x2 - y2);
    const float sh9  = 0.5900435899266435f * y * (3.0f * x2 - y2);
    const float sh10 = 2.890611442640554f  * x * y * z;
    const float sh11 = 0.4570457994644658f * y * (5.0f * z2 - 1.0f);
    const float sh12 = 0.3731763325901154f * z * (5.0f * z2 - 3.0f);
    const float sh13 = 0.4570457994644658f * x * (5.0f * z2 - 1.0f);
    const float sh14 = 1.445305721320277f  * z * (x2 - y2);
    const float sh15 = 0.5900435899266435f * x * (x2 - 3.0f * y2);

    float4* dst = shbuf + (size_t)sidx * 4;   // 64B-aligned, line-exact
    dst[0] = make_float4(sh12, sh13, sh14, sh15);   // rotated by 12
    dst[1] = make_float4(sh0,  sh1,  sh2,  sh3);
    dst[2] = make_float4(sh4,  sh5,  sh6,  sh7);
    dst[3] = make_float4(sh8,  sh9,  sh10, sh11);
}

// ---------------- fused gather + MLP: one wave per destination node ----------------
__global__ __launch_bounds__(256) void gather_mlp(
    const float* __restrict__ x,
    const float* __restrict__ pos,
    const int* __restrict__ ei,
    const int* __restrict__ counts,
    const int* __restrict__ bucket,
    const float* __restrict__ shbuf,
    const int* __restrict__ ovf_cnt,
    const int* __restrict__ ovf,
    const float* __restrict__ Wpre,  const float* __restrict__ bpre,
    const float* __restrict__ Wpost, const float* __restrict__ bpost,
    const float* __restrict__ Wsc,   const float* __restrict__ bsc,
    float* __restrict__ out)
{
    __shared__ float sWpre[IN_DIM * WPAD];
    __shared__ float sWpost[IN_DIM * WPAD];
    __shared__ float sWsc[IN_DIM * WPAD];
    __shared__ float sB[3 * IN_DIM];

    for (int t = threadIdx.x; t < IN_DIM * IN_DIM; t += 256) {
        const int r = t / IN_DIM, c = t - r * IN_DIM;
        sWpre[r * WPAD + c]  = Wpre[t];
        sWpost[r * WPAD + c] = Wpost[t];
        sWsc[r * WPAD + c]   = Wsc[t];
    }
    if (threadIdx.x < IN_DIM) {
        sB[threadIdx.x]              = bpre[threadIdx.x];
        sB[IN_DIM + threadIdx.x]     = bpost[threadIdx.x];
        sB[2 * IN_DIM + threadIdx.x] = bsc[threadIdx.x];
    }
    __syncthreads();

    const int lane   = threadIdx.x & 63;
    const int node   = (int)((blockIdx.x * blockDim.x + threadIdx.x) >> 6); // grid exact
    const int lane20 = min(lane, IN_DIM - 1);
    const int lane16 = lane & 15;

    // loop-invariant bpermute source lanes (feature f = lane + 64*ii, j = (f-20)>>4)
    const int j0 = (lane >= IN_DIM) ? ((lane - IN_DIM) >> 4) : 0;
    const int j1 = (lane + 44)  >> 4;
    const int j2 = (lane + 108) >> 4;
    const int j3 = (lane + 172) >> 4;
    const int j4 = (lane + 236) >> 4;
    const int j5 = (lane + 300) >> 4;

    const int cnt_raw = __builtin_amdgcn_readfirstlane(counts[node]);
    const int cnt = min(cnt_raw, CAP);

    // MLP input prefetch (independent of gather loop)
    const float xi = x[(size_t)node * IN_DIM + lane20];

    float acc0 = 0.f, acc1 = 0.f, acc2 = 0.f, acc3 = 0.f, acc4 = 0.f, acc5 = 0.f;
    float sum_s = 0.f;

    if (cnt > 0) {
        // coalesced pre-load of this wave's bucket (rows) into one register/lane
        const int rl = bucket[node * CAP + min(lane, cnt - 1)];
        const float* shb = shbuf + (size_t)node * CAP * 16 + lane16;

        int row = __builtin_amdgcn_readlane(rl, 0);
        float s_n  = x[(size_t)row * IN_DIM + lane20];
        float sh_n = shb[0];

        for (int i = 0; i < cnt; ++i) {
            const float s_c  = s_n;
            const float sh_c = sh_n;                 // per-lane sh[k] directly
            const int nid = min(i + 1, cnt - 1);     // branchless lookahead
            row  = __builtin_amdgcn_readlane(rl, nid);
            s_n  = x[(size_t)row * IN_DIM + lane20];
            sh_n = shb[(size_t)nid * 16];

            sum_s += s_c;                            // sender block (lanes<20 use it)
            acc0 = fmaf(__shfl(s_c, j0, 64), sh_c, acc0);
            acc1 = fmaf(__shfl(s_c, j1, 64), sh_c, acc1);
            acc2 = fmaf(__shfl(s_c, j2, 64), sh_c, acc2);
            acc3 = fmaf(__shfl(s_c, j3, 64), sh_c, acc3);
            acc4 = fmaf(__shfl(s_c, j4, 64), sh_c, acc4);
            acc5 = fmaf(__shfl(s_c, j5, 64), sh_c, acc5);
        }
    }

    // exact overflow fallback (cnt_raw > CAP unreachable for this distribution)
    if (cnt_raw > CAP) {
        const int m = *ovf_cnt;
        const int k = (lane + 12) & 15;
        for (int i = 0; i < m; ++i) {
            const int e = ovf[i];
            if (ei[N_EDGES + e] != node) continue;   // wave-uniform
            const int row = ei[e];
            const float rx = pos[node * 3 + 0] - pos[row * 3 + 0];
            const float ry = pos[node * 3 + 1] - pos[row * 3 + 1];
            const float rz = pos[node * 3 + 2] - pos[row * 3 + 2];
            const float rinv = rsqrtf(rx * rx + ry * ry + rz * rz + EPS_F);
            const float shk = sh_coeff(k, rx * rinv, ry * rinv, rz * rinv);
            const float s = x[(size_t)row * IN_DIM + lane20];
            sum_s += s;
            acc0 = fmaf(__shfl(s, j0, 64), shk, acc0);
            acc1 = fmaf(__shfl(s, j1, 64), shk, acc1);
            acc2 = fmaf(__shfl(s, j2, 64), shk, acc2);
            acc3 = fmaf(__shfl(s, j3, 64), shk, acc3);
            acc4 = fmaf(__shfl(s, j4, 64), shk, acc4);
            acc5 = fmaf(__shfl(s, j5, 64), shk, acc5);
        }
    }

    float* obase = out + (size_t)node * OUT_DIM + IN_DIM;   // aggr block, cols 20..359
    obase[lane]       = (lane < IN_DIM) ? sum_s : acc0;
    obase[lane + 64]  = acc1;
    obase[lane + 128] = acc2;
    obase[lane + 192] = acc3;
    obase[lane + 256] = acc4;
    if (lane < IN_DIM) obase[lane + 320] = acc5;

    // ---- fused node MLP (lane j < 20 computes output feature j) ----
    float h = sB[lane20];
#pragma unroll
    for (int kk = 0; kk < IN_DIM; ++kk)
        h = fmaf(__shfl(xi, kk, 64), sWpre[lane20 * WPAD + kk], h);
    h = fmaxf(h, 0.0f);

    float o = sB[IN_DIM + lane20] + sB[2 * IN_DIM + lane20];
#pragma unroll
    for (int kk = 0; kk < IN_DIM; ++kk) {
        o = fmaf(__shfl(h,  kk, 64), sWpost[lane20 * WPAD + kk], o);
        o = fmaf(__shfl(xi, kk, 64), sWsc[lane20 * WPAD + kk],  o);
    }
    if (lane < IN_DIM) out[(size_t)node * OUT_DIM + lane] = o;
}

extern "C" void kernel_launch(void* const* d_in, const int* in_sizes, int n_in,
                              void* d_out, int out_size, void* d_ws, size_t ws_size,
                              hipStream_t stream)
{
    const float* x     = (const float*)d_in[0];
    const float* pos   = (const float*)d_in[1];
    const int*   ei    = (const int*)d_in[2];
    const float* Wpre  = (const float*)d_in[3];
    const float* bpre  = (const float*)d_in[4];
    const float* Wpost = (const float*)d_in[5];
    const float* bpost = (const float*)d_in[6];
    const float* Wsc   = (const float*)d_in[7];
    const float* bsc   = (const float*)d_in[8];
    float* out = (float*)d_out;

    // ws layout: [shbuf: N*CAP*16 f32 = 81.9MB][counts: N][ovf_cnt: 1][ovf: E][bucket: N*CAP]
    float4* shbuf = (float4*)d_ws;                         // N_NODES*CAP*4 float4s
    int* ws_i    = (int*)(shbuf + (size_t)N_NODES * CAP * 4);
    int* counts  = ws_i;
    int* ovf_cnt = ws_i + N_NODES;
    int* ovf     = ws_i + N_NODES + 1;
    int* bucket  = ws_i + N_NODES + 1 + N_EDGES;

    hipMemsetAsync(counts, 0, (size_t)(N_NODES + 1) * sizeof(int), stream); // counts + ovf_cnt

    bucket_build_sh<<<(N_EDGES + 255) / 256, 256, 0, stream>>>(
        pos, ei, counts, ovf_cnt, ovf, bucket, shbuf);

    gather_mlp<<<(N_NODES * 64) / 256, 256, 0, stream>>>(   // exactly 5000 blocks
        x, pos, ei, counts, bucket, (const float*)shbuf, ovf_cnt, ovf,
        Wpre, bpre, Wpost, bpost, Wsc, bsc, out);
}

// Round 9
// 127.486 us; speedup vs baseline: 1.0644x; 1.0644x over previous
//
#include <hip/hip_runtime.h>

#define N_NODES 20000
#define N_EDGES 240000
#define IN_DIM  20
#define AGG_DIM 340   // 20 sender + 320 tp
#define OUT_DIM 360   // 20 mlp + 340 aggr
#define EPS_F   1e-12f
#define CAP     64    // bucket capacity per node (Binomial mean 12, max ~35)
#define EDGE_BLOCKS ((N_EDGES + 255) / 256)   // 938
#define MLP_BLOCKS  ((N_NODES + 255) / 256)   // 79

// switch version, used only in the (normally never-taken) overflow path
__device__ __forceinline__ float sh_coeff(int k, float xn, float yn, float zn) {
    const float x2 = xn * xn, y2 = yn * yn, z2 = zn * zn;
    switch (k) {
        case 0:  return 0.28209479177387814f;
        case 1:  return 0.4886025119029199f * yn;
        case 2:  return 0.4886025119029199f * zn;
        case 3:  return 0.4886025119029199f * xn;
        case 4:  return 1.0925484305920792f * xn * yn;
        case 5:  return 1.0925484305920792f * yn * zn;
        case 6:  return 0.31539156525252005f * (3.0f * z2 - 1.0f);
        case 7:  return 1.0925484305920792f * xn * zn;
        case 8:  return 0.5462742152960396f * (x2 - y2);
        case 9:  return 0.5900435899266435f * yn * (3.0f * x2 - y2);
        case 10: return 2.890611442640554f  * xn * yn * zn;
        case 11: return 0.4570457994644658f * yn * (5.0f * z2 - 1.0f);
        case 12: return 0.3731763325901154f * zn * (5.0f * z2 - 3.0f);
        case 13: return 0.4570457994644658f * xn * (5.0f * z2 - 1.0f);
        case 14: return 1.445305721320277f  * zn * (x2 - y2);
        default: return 0.5900435899266435f * xn * (x2 - 3.0f * y2); // k==15
    }
}

// ------- fused: bucket build + per-edge SH (thread/edge)  ||  node MLP (thread/node) -------
// shbuf layout: [(col*CAP + slot)][16], ROTATED by 12 so gather lane l reads
// element (l & 15) == sh[(l+12) & 15] directly.
__global__ __launch_bounds__(256) void bucket_sh_mlp(
    const float* __restrict__ pos,
    const int* __restrict__ ei,
    const float* __restrict__ x,
    const float* __restrict__ Wpre,  const float* __restrict__ bpre,
    const float* __restrict__ Wpost, const float* __restrict__ bpost,
    const float* __restrict__ Wsc,   const float* __restrict__ bsc,
    int* __restrict__ counts,      // [N_NODES]
    int* __restrict__ ovf_cnt,     // [1]
    int* __restrict__ ovf,         // [N_EDGES] (exact)
    int* __restrict__ bucket,      // [N_NODES * CAP] holds ROW
    float4* __restrict__ shbuf,    // [N_NODES * CAP * 4] (16 floats per slot)
    float* __restrict__ out)
{
    if ((int)blockIdx.x < EDGE_BLOCKS) {
        // ---------------- edge part ----------------
        const int e = (int)(blockIdx.x * 256 + threadIdx.x);
        if (e >= N_EDGES) return;
        const int row = ei[e];
        const int col = ei[N_EDGES + e];
        const int slot = atomicAdd(&counts[col], 1);
        if (slot >= CAP) { ovf[atomicAdd(ovf_cnt, 1)] = e; return; }

        const int sidx = col * CAP + slot;
        bucket[sidx] = row;

        const float rx = pos[col * 3 + 0] - pos[row * 3 + 0];
        const float ry = pos[col * 3 + 1] - pos[row * 3 + 1];
        const float rz = pos[col * 3 + 2] - pos[row * 3 + 2];
        const float rinv = rsqrtf(rx * rx + ry * ry + rz * rz + EPS_F);
        const float xx = rx * rinv, yy = ry * rinv, zz = rz * rinv;
        const float x2 = xx * xx, y2 = yy * yy, z2 = zz * zz;

        const float sh0  = 0.28209479177387814f;
        const float sh1  = 0.4886025119029199f * yy;
        const float sh2  = 0.4886025119029199f * zz;
        const float sh3  = 0.4886025119029199f * xx;
        const float sh4  = 1.0925484305920792f * xx * yy;
        const float sh5  = 1.0925484305920792f * yy * zz;
        const float sh6  = 0.31539156525252005f * (3.0f * z2 - 1.0f);
        const float sh7  = 1.0925484305920792f * xx * zz;
        const float sh8  = 0.5462742152960396f * (x2 - y2);
        const float sh9  = 0.5900435899266435f * yy * (3.0f * x2 - y2);
        const float sh10 = 2.890611442640554f  * xx * yy * zz;
        const float sh11 = 0.4570457994644658f * yy * (5.0f * z2 - 1.0f);
        const float sh12 = 0.3731763325901154f * zz * (5.0f * z2 - 3.0f);
        const float sh13 = 0.4570457994644658f * xx * (5.0f * z2 - 1.0f);
        const float sh14 = 1.445305721320277f  * zz * (x2 - y2);
        const float sh15 = 0.5900435899266435f * xx * (x2 - 3.0f * y2);

        float4* dst = shbuf + (size_t)sidx * 4;       // 64B-aligned, line-exact
        dst[0] = make_float4(sh12, sh13, sh14, sh15); // rotated by 12
        dst[1] = make_float4(sh0,  sh1,  sh2,  sh3);
        dst[2] = make_float4(sh4,  sh5,  sh6,  sh7);
        dst[3] = make_float4(sh8,  sh9,  sh10, sh11);
        return;
    }

    // ---------------- MLP part: thread per node ----------------
    __shared__ float sWpre[IN_DIM * IN_DIM];
    __shared__ float sWpost[IN_DIM * IN_DIM];
    __shared__ float sWsc[IN_DIM * IN_DIM];
    __shared__ float sb[3 * IN_DIM];

    for (int t = threadIdx.x; t < IN_DIM * IN_DIM; t += 256) {
        sWpre[t]  = Wpre[t];
        sWpost[t] = Wpost[t];
        sWsc[t]   = Wsc[t];
    }
    if (threadIdx.x < IN_DIM) {
        sb[threadIdx.x]              = bpre[threadIdx.x];
        sb[IN_DIM + threadIdx.x]     = bpost[threadIdx.x];
        sb[2 * IN_DIM + threadIdx.x] = bsc[threadIdx.x];
    }
    __syncthreads();

    const int i = (int)((blockIdx.x - EDGE_BLOCKS) * 256 + threadIdx.x);
    if (i >= N_NODES) return;

    float xi[IN_DIM], h[IN_DIM];
#pragma unroll
    for (int j = 0; j < IN_DIM; ++j) xi[j] = x[(size_t)i * IN_DIM + j];

#pragma unroll
    for (int j = 0; j < IN_DIM; ++j) {
        float a = sb[j];
#pragma unroll
        for (int kk = 0; kk < IN_DIM; ++kk) a = fmaf(xi[kk], sWpre[j * IN_DIM + kk], a);
        h[j] = fmaxf(a, 0.0f);
    }
#pragma unroll
    for (int j = 0; j < IN_DIM; ++j) {
        float a = sb[IN_DIM + j] + sb[2 * IN_DIM + j];
#pragma unroll
        for (int kk = 0; kk < IN_DIM; ++kk) {
            a = fmaf(h[kk],  sWpost[j * IN_DIM + kk], a);
            a = fmaf(xi[kk], sWsc[j * IN_DIM + kk],  a);
        }
        out[(size_t)i * OUT_DIM + j] = a;
    }
}

// ---------------- gather: one wave per destination node, 4-edge chunks ----------------
__global__ __launch_bounds__(256) void node_gather(
    const float* __restrict__ x,
    const float* __restrict__ pos,
    const int* __restrict__ ei,
    const int* __restrict__ counts,
    const int* __restrict__ bucket,
    const float* __restrict__ shbuf,
    const int* __restrict__ ovf_cnt,
    const int* __restrict__ ovf,
    float* __restrict__ out)
{
    const int lane   = threadIdx.x & 63;
    const int node   = (int)((blockIdx.x * blockDim.x + threadIdx.x) >> 6); // grid exact
    const int lane20 = min(lane, IN_DIM - 1);
    const int lane16 = lane & 15;

    // loop-invariant bpermute source lanes (feature f = lane + 64*ii, j = (f-20)>>4)
    const int j0 = (lane >= IN_DIM) ? ((lane - IN_DIM) >> 4) : 0;
    const int j1 = (lane + 44)  >> 4;
    const int j2 = (lane + 108) >> 4;
    const int j3 = (lane + 172) >> 4;
    const int j4 = (lane + 236) >> 4;
    const int j5 = (lane + 300) >> 4;

    const int cnt_raw = __builtin_amdgcn_readfirstlane(counts[node]);
    const int cnt = min(cnt_raw, CAP);

    float acc0 = 0.f, acc1 = 0.f, acc2 = 0.f, acc3 = 0.f, acc4 = 0.f, acc5 = 0.f;
    float sum_s = 0.f;

    if (cnt > 0) {
        // coalesced pre-load of this wave's bucket (rows) into one register/lane
        const int rl = bucket[node * CAP + min(lane, cnt - 1)];
        const float* shb = shbuf + (size_t)node * CAP * 16 + lane16;

        for (int base = 0; base < cnt; base += 4) {
            const int i1 = min(base + 1, cnt - 1);
            const int i2 = min(base + 2, cnt - 1);
            const int i3 = min(base + 3, cnt - 1);
            const int r0 = __builtin_amdgcn_readlane(rl, base);
            const int r1 = __builtin_amdgcn_readlane(rl, i1);
            const int r2 = __builtin_amdgcn_readlane(rl, i2);
            const int r3 = __builtin_amdgcn_readlane(rl, i3);

            // 8 independent loads in flight
            float sA = x[(size_t)r0 * IN_DIM + lane20];
            float sB = x[(size_t)r1 * IN_DIM + lane20];
            float sC = x[(size_t)r2 * IN_DIM + lane20];
            float sD = x[(size_t)r3 * IN_DIM + lane20];
            const float shA = shb[(size_t)base * 16];
            const float shB = shb[(size_t)i1 * 16];
            const float shC = shb[(size_t)i2 * 16];
            const float shD = shb[(size_t)i3 * 16];

            // zero-mask tail duplicates (wave-uniform predicates);
            // zeroed s kills sender, acc0 and all tp contributions identically
            sB = (base + 1 < cnt) ? sB : 0.0f;
            sC = (base + 2 < cnt) ? sC : 0.0f;
            sD = (base + 3 < cnt) ? sD : 0.0f;

#define ACCUM(S, SH)                                      \
            sum_s += (S);                                 \
            acc0 = fmaf(__shfl((S), j0, 64), (SH), acc0); \
            acc1 = fmaf(__shfl((S), j1, 64), (SH), acc1); \
            acc2 = fmaf(__shfl((S), j2, 64), (SH), acc2); \
            acc3 = fmaf(__shfl((S), j3, 64), (SH), acc3); \
            acc4 = fmaf(__shfl((S), j4, 64), (SH), acc4); \
            acc5 = fmaf(__shfl((S), j5, 64), (SH), acc5);

            ACCUM(sA, shA)
            ACCUM(sB, shB)
            ACCUM(sC, shC)
            ACCUM(sD, shD)
        }
    }

    // exact overflow fallback (cnt_raw > CAP unreachable for this distribution)
    if (cnt_raw > CAP) {
        const int m = *ovf_cnt;
        const int k = (lane + 12) & 15;
        for (int i = 0; i < m; ++i) {
            const int e = ovf[i];
            if (ei[N_EDGES + e] != node) continue;   // wave-uniform
            const int row = ei[e];
            const float rx = pos[node * 3 + 0] - pos[row * 3 + 0];
            const float ry = pos[node * 3 + 1] - pos[row * 3 + 1];
            const float rz = pos[node * 3 + 2] - pos[row * 3 + 2];
            const float rinv = rsqrtf(rx * rx + ry * ry + rz * rz + EPS_F);
            const float shk = sh_coeff(k, rx * rinv, ry * rinv, rz * rinv);
            const float s = x[(size_t)row * IN_DIM + lane20];
            ACCUM(s, shk)
        }
    }
#undef ACCUM

    float* obase = out + (size_t)node * OUT_DIM + IN_DIM;   // aggr block, cols 20..359
    obase[lane]       = (lane < IN_DIM) ? sum_s : acc0;
    obase[lane + 64]  = acc1;
    obase[lane + 128] = acc2;
    obase[lane + 192] = acc3;
    obase[lane + 256] = acc4;
    if (lane < IN_DIM) obase[lane + 320] = acc5;
}

extern "C" void kernel_launch(void* const* d_in, const int* in_sizes, int n_in,
                              void* d_out, int out_size, void* d_ws, size_t ws_size,
                              hipStream_t stream)
{
    const float* x     = (const float*)d_in[0];
    const float* pos   = (const float*)d_in[1];
    const int*   ei    = (const int*)d_in[2];
    const float* Wpre  = (const float*)d_in[3];
    const float* bpre  = (const float*)d_in[4];
    const float* Wpost = (const float*)d_in[5];
    const float* bpost = (const float*)d_in[6];
    const float* Wsc   = (const float*)d_in[7];
    const float* bsc   = (const float*)d_in[8];
    float* out = (float*)d_out;

    // ws layout: [shbuf: N*CAP*16 f32 = 81.9MB][counts: N][ovf_cnt: 1][ovf: E][bucket: N*CAP]
    float4* shbuf = (float4*)d_ws;                         // N_NODES*CAP*4 float4s
    int* ws_i    = (int*)(shbuf + (size_t)N_NODES * CAP * 4);
    int* counts  = ws_i;
    int* ovf_cnt = ws_i + N_NODES;
    int* ovf     = ws_i + N_NODES + 1;
    int* bucket  = ws_i + N_NODES + 1 + N_EDGES;

    hipMemsetAsync(counts, 0, (size_t)(N_NODES + 1) * sizeof(int), stream); // counts + ovf_cnt

    bucket_sh_mlp<<<EDGE_BLOCKS + MLP_BLOCKS, 256, 0, stream>>>(
        pos, ei, x, Wpre, bpre, Wpost, bpost, Wsc, bsc,
        counts, ovf_cnt, ovf, bucket, shbuf, out);

    node_gather<<<(N_NODES * 64) / 256, 256, 0, stream>>>(   // exactly 5000 blocks
        x, pos, ei, counts, bucket, (const float*)shbuf, ovf_cnt, ovf, out);
}

// Round 10
// 126.708 us; speedup vs baseline: 1.0710x; 1.0061x over previous
//
#include <hip/hip_runtime.h>

#define N_NODES 20000
#define N_EDGES 240000
#define IN_DIM  20
#define AGG_DIM 340   // 20 sender + 320 tp
#define OUT_DIM 360   // 20 mlp + 340 aggr
#define EPS_F   1e-12f
#define CAP     64    // bucket capacity per node (Binomial mean 12, max ~35)
#define EDGE_BLOCKS ((N_EDGES + 255) / 256)   // 938
#define MLP_BLOCKS  ((N_NODES + 255) / 256)   // 79

typedef _Float16 half8 __attribute__((ext_vector_type(8)));

// switch version, used only in the (normally never-taken) overflow path
__device__ __forceinline__ float sh_coeff(int k, float xn, float yn, float zn) {
    const float x2 = xn * xn, y2 = yn * yn, z2 = zn * zn;
    switch (k) {
        case 0:  return 0.28209479177387814f;
        case 1:  return 0.4886025119029199f * yn;
        case 2:  return 0.4886025119029199f * zn;
        case 3:  return 0.4886025119029199f * xn;
        case 4:  return 1.0925484305920792f * xn * yn;
        case 5:  return 1.0925484305920792f * yn * zn;
        case 6:  return 0.31539156525252005f * (3.0f * z2 - 1.0f);
        case 7:  return 1.0925484305920792f * xn * zn;
        case 8:  return 0.5462742152960396f * (x2 - y2);
        case 9:  return 0.5900435899266435f * yn * (3.0f * x2 - y2);
        case 10: return 2.890611442640554f  * xn * yn * zn;
        case 11: return 0.4570457994644658f * yn * (5.0f * z2 - 1.0f);
        case 12: return 0.3731763325901154f * zn * (5.0f * z2 - 3.0f);
        case 13: return 0.4570457994644658f * xn * (5.0f * z2 - 1.0f);
        case 14: return 1.445305721320277f  * zn * (x2 - y2);
        default: return 0.5900435899266435f * xn * (x2 - 3.0f * y2); // k==15
    }
}

// ------- fused: bucket build + per-edge SH (thread/edge)  ||  node MLP (thread/node) -------
// shbuf: fp16[ (col*CAP+slot) ][16], ROTATED by 12 so gather lane l reads
// element (l & 15) == sh[(l+12) & 15] directly.
__global__ __launch_bounds__(256) void bucket_sh_mlp(
    const float* __restrict__ pos,
    const int* __restrict__ ei,
    const float* __restrict__ x,
    const float* __restrict__ Wpre,  const float* __restrict__ bpre,
    const float* __restrict__ Wpost, const float* __restrict__ bpost,
    const float* __restrict__ Wsc,   const float* __restrict__ bsc,
    int* __restrict__ counts,      // [N_NODES]
    int* __restrict__ ovf_cnt,     // [1]
    int* __restrict__ ovf,         // [N_EDGES] (exact)
    int* __restrict__ bucket,      // [N_NODES * CAP] holds ROW
    half8* __restrict__ shbuf,     // [N_NODES * CAP * 2] (16 halves per slot)
    float* __restrict__ out)
{
    if ((int)blockIdx.x < EDGE_BLOCKS) {
        // ---------------- edge part ----------------
        const int e = (int)(blockIdx.x * 256 + threadIdx.x);
        if (e >= N_EDGES) return;
        const int row = ei[e];
        const int col = ei[N_EDGES + e];
        const int slot = atomicAdd(&counts[col], 1);
        if (slot >= CAP) { ovf[atomicAdd(ovf_cnt, 1)] = e; return; }

        const int sidx = col * CAP + slot;
        bucket[sidx] = row;

        const float rx = pos[col * 3 + 0] - pos[row * 3 + 0];
        const float ry = pos[col * 3 + 1] - pos[row * 3 + 1];
        const float rz = pos[col * 3 + 2] - pos[row * 3 + 2];
        const float rinv = rsqrtf(rx * rx + ry * ry + rz * rz + EPS_F);
        const float xx = rx * rinv, yy = ry * rinv, zz = rz * rinv;
        const float x2 = xx * xx, y2 = yy * yy, z2 = zz * zz;

        const float sh0  = 0.28209479177387814f;
        const float sh1  = 0.4886025119029199f * yy;
        const float sh2  = 0.4886025119029199f * zz;
        const float sh3  = 0.4886025119029199f * xx;
        const float sh4  = 1.0925484305920792f * xx * yy;
        const float sh5  = 1.0925484305920792f * yy * zz;
        const float sh6  = 0.31539156525252005f * (3.0f * z2 - 1.0f);
        const float sh7  = 1.0925484305920792f * xx * zz;
        const float sh8  = 0.5462742152960396f * (x2 - y2);
        const float sh9  = 0.5900435899266435f * yy * (3.0f * x2 - y2);
        const float sh10 = 2.890611442640554f  * xx * yy * zz;
        const float sh11 = 0.4570457994644658f * yy * (5.0f * z2 - 1.0f);
        const float sh12 = 0.3731763325901154f * zz * (5.0f * z2 - 3.0f);
        const float sh13 = 0.4570457994644658f * xx * (5.0f * z2 - 1.0f);
        const float sh14 = 1.445305721320277f  * zz * (x2 - y2);
        const float sh15 = 0.5900435899266435f * xx * (x2 - 3.0f * y2);

        // rotated by 12: element (l&15) holds sh[(l+12)&15]
        const half8 v0 = { (_Float16)sh12, (_Float16)sh13, (_Float16)sh14, (_Float16)sh15,
                           (_Float16)sh0,  (_Float16)sh1,  (_Float16)sh2,  (_Float16)sh3 };
        const half8 v1 = { (_Float16)sh4,  (_Float16)sh5,  (_Float16)sh6,  (_Float16)sh7,
                           (_Float16)sh8,  (_Float16)sh9,  (_Float16)sh10, (_Float16)sh11 };
        half8* dst = shbuf + (size_t)sidx * 2;   // 32B per slot
        dst[0] = v0;
        dst[1] = v1;
        return;
    }

    // ---------------- MLP part: thread per node ----------------
    __shared__ float sWpre[IN_DIM * IN_DIM];
    __shared__ float sWpost[IN_DIM * IN_DIM];
    __shared__ float sWsc[IN_DIM * IN_DIM];
    __shared__ float sb[3 * IN_DIM];

    for (int t = threadIdx.x; t < IN_DIM * IN_DIM; t += 256) {
        sWpre[t]  = Wpre[t];
        sWpost[t] = Wpost[t];
        sWsc[t]   = Wsc[t];
    }
    if (threadIdx.x < IN_DIM) {
        sb[threadIdx.x]              = bpre[threadIdx.x];
        sb[IN_DIM + threadIdx.x]     = bpost[threadIdx.x];
        sb[2 * IN_DIM + threadIdx.x] = bsc[threadIdx.x];
    }
    __syncthreads();

    const int i = (int)((blockIdx.x - EDGE_BLOCKS) * 256 + threadIdx.x);
    if (i >= N_NODES) return;

    float xi[IN_DIM], h[IN_DIM];
#pragma unroll
    for (int j = 0; j < IN_DIM; ++j) xi[j] = x[(size_t)i * IN_DIM + j];

#pragma unroll
    for (int j = 0; j < IN_DIM; ++j) {
        float a = sb[j];
#pragma unroll
        for (int kk = 0; kk < IN_DIM; ++kk) a = fmaf(xi[kk], sWpre[j * IN_DIM + kk], a);
        h[j] = fmaxf(a, 0.0f);
    }
#pragma unroll
    for (int j = 0; j < IN_DIM; ++j) {
        float a = sb[IN_DIM + j] + sb[2 * IN_DIM + j];
#pragma unroll
        for (int kk = 0; kk < IN_DIM; ++kk) {
            a = fmaf(h[kk],  sWpost[j * IN_DIM + kk], a);
            a = fmaf(xi[kk], sWsc[j * IN_DIM + kk],  a);
        }
        out[(size_t)i * OUT_DIM + j] = a;
    }
}

// -------- gather: one wave per node, 4-edge chunks, 2-stage pipeline --------
__global__ __launch_bounds__(256) void node_gather(
    const float* __restrict__ x,
    const float* __restrict__ pos,
    const int* __restrict__ ei,
    const int* __restrict__ counts,
    const int* __restrict__ bucket,
    const _Float16* __restrict__ shbuf,
    const int* __restrict__ ovf_cnt,
    const int* __restrict__ ovf,
    float* __restrict__ out)
{
    const int lane   = threadIdx.x & 63;
    const int node   = (int)((blockIdx.x * blockDim.x + threadIdx.x) >> 6); // grid exact
    const int lane20 = min(lane, IN_DIM - 1);
    const int lane16 = lane & 15;

    // loop-invariant bpermute source lanes (feature f = lane + 64*ii, j = (f-20)>>4)
    const int j0 = (lane >= IN_DIM) ? ((lane - IN_DIM) >> 4) : 0;
    const int j1 = (lane + 44)  >> 4;
    const int j2 = (lane + 108) >> 4;
    const int j3 = (lane + 172) >> 4;
    const int j4 = (lane + 236) >> 4;
    const int j5 = (lane + 300) >> 4;

    const int cnt_raw = __builtin_amdgcn_readfirstlane(counts[node]);
    const int cnt = min(cnt_raw, CAP);

    float acc0 = 0.f, acc1 = 0.f, acc2 = 0.f, acc3 = 0.f, acc4 = 0.f, acc5 = 0.f;
    float sum_s = 0.f;

#define ACCUM(S, SH)                                      \
    do {                                                  \
        sum_s += (S);                                     \
        acc0 = fmaf(__shfl((S), j0, 64), (SH), acc0);     \
        acc1 = fmaf(__shfl((S), j1, 64), (SH), acc1);     \
        acc2 = fmaf(__shfl((S), j2, 64), (SH), acc2);     \
        acc3 = fmaf(__shfl((S), j3, 64), (SH), acc3);     \
        acc4 = fmaf(__shfl((S), j4, 64), (SH), acc4);     \
        acc5 = fmaf(__shfl((S), j5, 64), (SH), acc5);     \
    } while (0)

    if (cnt > 0) {
        // coalesced pre-load of this wave's bucket (rows) into one register/lane
        const int rl = bucket[node * CAP + min(lane, cnt - 1)];
        const _Float16* shb = shbuf + (size_t)node * CAP * 16 + lane16;

#define LOADCHUNK(B, S0, S1, S2, S3, H0, H1, H2, H3)                      \
    do {                                                                  \
        const int q1 = min((B) + 1, cnt - 1);                             \
        const int q2 = min((B) + 2, cnt - 1);                             \
        const int q3 = min((B) + 3, cnt - 1);                             \
        const int r0 = __builtin_amdgcn_readlane(rl, (B));                \
        const int r1 = __builtin_amdgcn_readlane(rl, q1);                 \
        const int r2 = __builtin_amdgcn_readlane(rl, q2);                 \
        const int r3 = __builtin_amdgcn_readlane(rl, q3);                 \
        S0 = x[(size_t)r0 * IN_DIM + lane20];                             \
        S1 = x[(size_t)r1 * IN_DIM + lane20];                             \
        S2 = x[(size_t)r2 * IN_DIM + lane20];                             \
        S3 = x[(size_t)r3 * IN_DIM + lane20];                             \
        H0 = (float)shb[(size_t)(B) * 16];                                \
        H1 = (float)shb[(size_t)q1 * 16];                                 \
        H2 = (float)shb[(size_t)q2 * 16];                                 \
        H3 = (float)shb[(size_t)q3 * 16];                                 \
    } while (0)

        float sA, sB, sC, sD, shA, shB, shC, shD;   // current chunk
        float tA, tB, tC, tD, uA, uB, uC, uD;       // next chunk (pipeline)

        LOADCHUNK(0, sA, sB, sC, sD, shA, shB, shC, shD);

        for (int base = 0; base < cnt; base += 4) {
            const int nb = base + 4;
            const bool have_next = nb < cnt;         // wave-uniform
            if (have_next)
                LOADCHUNK(nb, tA, tB, tC, tD, uA, uB, uC, uD);

            // zero-mask tail duplicates; zeroed s kills sender/tp identically
            const float mB = (base + 1 < cnt) ? sB : 0.0f;
            const float mC = (base + 2 < cnt) ? sC : 0.0f;
            const float mD = (base + 3 < cnt) ? sD : 0.0f;

            ACCUM(sA, shA);
            ACCUM(mB, shB);
            ACCUM(mC, shC);
            ACCUM(mD, shD);

            if (have_next) {
                sA = tA; sB = tB; sC = tC; sD = tD;
                shA = uA; shB = uB; shC = uC; shD = uD;
            }
        }
#undef LOADCHUNK
    }

    // exact overflow fallback (cnt_raw > CAP unreachable for this distribution)
    if (cnt_raw > CAP) {
        const int m = *ovf_cnt;
        const int k = (lane + 12) & 15;
        for (int i = 0; i < m; ++i) {
            const int e = ovf[i];
            if (ei[N_EDGES + e] != node) continue;   // wave-uniform
            const int row = ei[e];
            const float rx = pos[node * 3 + 0] - pos[row * 3 + 0];
            const float ry = pos[node * 3 + 1] - pos[row * 3 + 1];
            const float rz = pos[node * 3 + 2] - pos[row * 3 + 2];
            const float rinv = rsqrtf(rx * rx + ry * ry + rz * rz + EPS_F);
            const float shk = sh_coeff(k, rx * rinv, ry * rinv, rz * rinv);
            const float s = x[(size_t)row * IN_DIM + lane20];
            ACCUM(s, shk);
        }
    }
#undef ACCUM

    float* obase = out + (size_t)node * OUT_DIM + IN_DIM;   // aggr block, cols 20..359
    obase[lane]       = (lane < IN_DIM) ? sum_s : acc0;
    obase[lane + 64]  = acc1;
    obase[lane + 128] = acc2;
    obase[lane + 192] = acc3;
    obase[lane + 256] = acc4;
    if (lane < IN_DIM) obase[lane + 320] = acc5;
}

extern "C" void kernel_launch(void* const* d_in, const int* in_sizes, int n_in,
                              void* d_out, int out_size, void* d_ws, size_t ws_size,
                              hipStream_t stream)
{
    const float* x     = (const float*)d_in[0];
    const float* pos   = (const float*)d_in[1];
    const int*   ei    = (const int*)d_in[2];
    const float* Wpre  = (const float*)d_in[3];
    const float* bpre  = (const float*)d_in[4];
    const float* Wpost = (const float*)d_in[5];
    const float* bpost = (const float*)d_in[6];
    const float* Wsc   = (const float*)d_in[7];
    const float* bsc   = (const float*)d_in[8];
    float* out = (float*)d_out;

    // ws layout: [shbuf: N*CAP*16 fp16 = 41MB][counts: N][ovf_cnt: 1][ovf: E][bucket: N*CAP]
    half8* shbuf = (half8*)d_ws;                           // N_NODES*CAP*2 half8s
    int* ws_i    = (int*)((char*)d_ws + (size_t)N_NODES * CAP * 16 * sizeof(_Float16));
    int* counts  = ws_i;
    int* ovf_cnt = ws_i + N_NODES;
    int* ovf     = ws_i + N_NODES + 1;
    int* bucket  = ws_i + N_NODES + 1 + N_EDGES;

    hipMemsetAsync(counts, 0, (size_t)(N_NODES + 1) * sizeof(int), stream); // counts + ovf_cnt

    bucket_sh_mlp<<<EDGE_BLOCKS + MLP_BLOCKS, 256, 0, stream>>>(
        pos, ei, x, Wpre, bpre, Wpost, bpost, Wsc, bsc,
        counts, ovf_cnt, ovf, bucket, shbuf, out);

    node_gather<<<(N_NODES * 64) / 256, 256, 0, stream>>>(   // exactly 5000 blocks
        x, pos, ei, counts, bucket, (const _Float16*)shbuf, ovf_cnt, ovf, out);
}